// Round 1
// baseline (374.048 us; speedup 1.0000x reference)
//
#include <hip/hip_runtime.h>

#define TT 512
#define DD 16
#define HH 48
#define BT 4       // batch rows per block -> 512 blocks = 2 independent blocks/CU
#define NTHR 384   // 6 waves; every lane owns exactly one cell (4b x 48u x 2 layers)
#define CHUNK 64   // timesteps of x resident in LDS ring
#define RS 72      // ring tile stride in ushorts (64 payload + 8 pad: bank-uniform refill writes)

// LDS (ushort units):
//  [0, XB)            x-ring: 64 tiles x RS (tile = 2 kgrp x 4 cols x 8, 8 pad)
//  [XB, XB+768)       B dbuf: 2 parities x 12 kgrp x 32 (4 physical cols = batch)
//    K-space (L0): k0-47 h1prev | k48-63 x (read from ring, not stored)
//    K-space (L1): k0-47 h1     | k48-95 h2prev
//    k0-47 SHARED (h1): one write serves both layers' MFMA cols.
#define XB (CHUNK * RS)          // 4608
#define PS 384                   // parity stride (12 kgrp x 32)
#define STOT (XB + 2 * PS)       // 5376

typedef short bf8v __attribute__((ext_vector_type(8)));   // 8 x bf16 bits
typedef float f32x4 __attribute__((ext_vector_type(4)));

__device__ __forceinline__ ushort bfb(float f) {
    return __builtin_bit_cast(ushort, (__bf16)f);
}

// sigmoid for the FC epilogue only
__device__ __forceinline__ float sigf(float x) {
    float e = __builtin_amdgcn_exp2f(-1.4426950408889634f * x);
    return __builtin_amdgcn_rcpf(1.0f + e);
}

// LDS-only barrier (no global ops in flight across bodies; refill drains via __syncthreads)
__device__ __forceinline__ void barrier_lds() {
    asm volatile("s_waitcnt lgkmcnt(0)\ns_barrier" ::: "memory");
}

__global__ __launch_bounds__(NTHR, 3)
void lstm_kernel(const float* __restrict__ x,
                 const float* __restrict__ Wih0, const float* __restrict__ Whh0,
                 const float* __restrict__ bih0, const float* __restrict__ bhh0,
                 const float* __restrict__ Wih1, const float* __restrict__ Whh1,
                 const float* __restrict__ bih1, const float* __restrict__ bhh1,
                 const float* __restrict__ fcw, const float* __restrict__ fcb,
                 float* __restrict__ out)
{
    __shared__ alignas(16) ushort S[STOT];
    __shared__ float outl[BT][HH];

    const int tid  = threadIdx.x;
    const int lane = tid & 63;
    const int wave = tid >> 6;
    const int b0   = blockIdx.x * BT;

    // col roles: b = colq&3, layer = (colq>>2)&1, unit-tile = colq>>3
    const int colq = lane & 15;
    const int quad = lane >> 4;
    const int b    = colq & 3;
    const bool Lb  = ((colq >> 2) & 1) != 0;   // 0: L0 cell, 1: L1 cell (batch b)
    const bool Tq  = (colq >= 8);              // unit tile within wave
    const int u    = wave * 8 + (Tq ? 4 : 0) + quad;   // unit owned: acc[r] = gate r of u

    const float L2E = 1.4426950408889634f;

    // ---- loop-invariant LDS addresses (ushort units) ----
    const int fbm = b * 8;                         // col base (16 cols mirror onto 4)
    const bool ringlane = (quad >= 2) && !Lb;      // v1 lanes that read x from the ring
    const int r0E = XB + quad * 32 + fbm;          // k0-31  (h1, mirror-broadcast)
    const int r0O = r0E + PS;
    const int r1statE = XB + (4 + quad) * 32 + fbm; // k32-63 static (h1 u32-47 / h2prev u0-15)
    const int r1statO = r1statE + PS;
    const int r2E = XB + (8 + quad) * 32 + fbm;    // k64-95 (h2prev u16-47, mirror)
    const int r2O = r2E + PS;
    const int r1ring0 = (quad - 2) * 32 + fbm;     // k48-63 = x, ring tile 0 base
    const int inc = ringlane ? 2 * RS : 0;         // ring advance per body pair
    const int kk = Lb ? 48 + u : u;                // write: L0 h1 (k=u), L1 h2 (k=48+u)
    const int woff = (kk >> 3) * 32 + fbm + (kk & 7);
    const int wE = XB + PS + woff;                 // parity-0 body writes parity 1
    const int wO = XB + woff;

    // ---- C-operand biases: acc reg r = gate type r of unit ----
    f32x4 bias00, bias01, bias10, bias11;
    {
        const int u0 = wave * 8 + quad;
        const int u1 = u0 + 4;
#pragma unroll
        for (int r = 0; r < 4; ++r) {
            bias00[r] = bih0[r * 48 + u0] + bhh0[r * 48 + u0];
            bias01[r] = bih0[r * 48 + u1] + bhh0[r * 48 + u1];
            bias10[r] = bih1[r * 48 + u0] + bhh1[r * 48 + u0];
            bias11[r] = bih1[r * 48 + u1] + bhh1[r * 48 + u1];
        }
    }

    // ---- step-invariant weight A-fragments, two unit tiles per wave ----
    // A-frag: lane holds A[m=colq][k=quad*8+j]; interleaved gate rows -> PyTorch gi
    bf8v w0k0_0, w0k1_0, w1k0_0, w1k1_0, w1k2_0;
    bf8v w0k0_1, w0k1_1, w1k0_1, w1k1_1, w1k2_1;
#define LOADW(GI, W0K0, W0K1, W1K0, W1K1, W1K2) { \
        bf8v w; \
        _Pragma("unroll") \
        for (int j = 0; j < 8; ++j) {      /* L0 k0-31 -> Whh0 (h1prev) */ \
            w[j] = (short)bfb(Whh0[(GI) * 48 + quad * 8 + j]); \
        } \
        W0K0 = w; \
        _Pragma("unroll") \
        for (int j = 0; j < 8; ++j) {      /* L0 k32-63: k<48 Whh0, else Wih0 (x) */ \
            int k = 32 + quad * 8 + j; \
            float v = (k < 48) ? Whh0[(GI) * 48 + k] : Wih0[(GI) * 16 + (k - 48)]; \
            w[j] = (short)bfb(v); \
        } \
        W0K1 = w; \
        _Pragma("unroll") \
        for (int j = 0; j < 8; ++j) {      /* L1 k0-31 -> Wih1 (h1) */ \
            w[j] = (short)bfb(Wih1[(GI) * 48 + quad * 8 + j]); \
        } \
        W1K0 = w; \
        _Pragma("unroll") \
        for (int j = 0; j < 8; ++j) {      /* L1 k32-63: k<48 Wih1, else Whh1 (h2prev) */ \
            int k = 32 + quad * 8 + j; \
            float v = (k < 48) ? Wih1[(GI) * 48 + k] : Whh1[(GI) * 48 + (k - 48)]; \
            w[j] = (short)bfb(v); \
        } \
        W1K1 = w; \
        _Pragma("unroll") \
        for (int j = 0; j < 8; ++j) {      /* L1 k64-95 -> Whh1 (h2prev u16-47) */ \
            w[j] = (short)bfb(Whh1[(GI) * 48 + 16 + quad * 8 + j]); \
        } \
        W1K2 = w; \
    }
    {
        const int gi0 = (colq & 3) * 48 + wave * 8 + (colq >> 2);
        const int gi1 = gi0 + 4;
        LOADW(gi0, w0k0_0, w0k1_0, w1k0_0, w1k1_0, w1k2_0)
        LOADW(gi1, w0k0_1, w0k1_1, w1k0_1, w1k1_1, w1k2_1)
    }
#undef LOADW

    // ---- init: zero all of S (h1/h2prev start at 0; junk cols bounded) ----
    {
        uint* p = (uint*)S;
        for (int i = tid; i < STOT / 2; i += NTHR) p[i] = 0;
    }
    __syncthreads();

    float c = 0.f;     // L0 lanes: c0; L1 lanes: c1
    float hv = 0.f;

#define MFMA(A, B, C) __builtin_amdgcn_mfma_f32_16x16x32_bf16(A, B, C, 0, 0, 0)

    // Cell update, rcp-fused (8 transcendentals):
    //   sig(i)*tanh(g) = (1-eg)*rcp((1+ei)(1+eg)),  eg = exp2(-2*L2E*g), ei = exp2(-L2E*i)
    //   cn = rcp(1+ef)*c + above ; h = (1-ec)*rcp((1+eo)(1+ec))
    // body t: L0(t) + L1(t-1); 3 ds_read_b128, 10 MFMA (2 unit tiles), 1 cell, 1 ds_write_b16
#define BODY(V0A, V1A, V2A, WA, DOL1) { \
        bf8v v0 = *(const bf8v*)&S[V0A]; \
        bf8v v1 = *(const bf8v*)&S[V1A]; \
        bf8v v2 = *(const bf8v*)&S[V2A]; \
        f32x4 a00 = MFMA(w0k0_0, v0, bias00); \
        a00 = MFMA(w0k1_0, v1, a00); \
        f32x4 a01 = MFMA(w0k0_1, v0, bias01); \
        a01 = MFMA(w0k1_1, v1, a01); \
        f32x4 pre; \
        if (DOL1) { \
            f32x4 a10 = MFMA(w1k0_0, v0, bias10); \
            a10 = MFMA(w1k1_0, v1, a10); \
            a10 = MFMA(w1k2_0, v2, a10); \
            f32x4 a11 = MFMA(w1k0_1, v0, bias11); \
            a11 = MFMA(w1k1_1, v1, a11); \
            a11 = MFMA(w1k2_1, v2, a11); \
            _Pragma("unroll") \
            for (int r = 0; r < 4; ++r) { \
                float l0 = Tq ? a01[r] : a00[r]; \
                float l1 = Tq ? a11[r] : a10[r]; \
                pre[r] = Lb ? l1 : l0; \
            } \
        } else { \
            _Pragma("unroll") \
            for (int r = 0; r < 4; ++r) pre[r] = Tq ? a01[r] : a00[r]; \
        } \
        float ei = __builtin_amdgcn_exp2f(-L2E * pre[0]); \
        float ef = __builtin_amdgcn_exp2f(-L2E * pre[1]); \
        float eg = __builtin_amdgcn_exp2f(-2.0f * L2E * pre[2]); \
        float eo = __builtin_amdgcn_exp2f(-L2E * pre[3]); \
        float rig = __builtin_amdgcn_rcpf((1.0f + ei) * (1.0f + eg)); \
        float rf  = __builtin_amdgcn_rcpf(1.0f + ef); \
        float cn = __builtin_fmaf(rf, c, (1.0f - eg) * rig); \
        if (!DOL1) cn = Lb ? c : cn;   /* peel: keep L1 state at 0 */ \
        c = cn; \
        float ec = __builtin_amdgcn_exp2f(-2.0f * L2E * cn); \
        float roc = __builtin_amdgcn_rcpf((1.0f + eo) * (1.0f + ec)); \
        hv = (1.0f - ec) * roc; \
        ushort hb = bfb(hv); \
        if (!Lb) { S[WA] = hb; } \
        else if (DOL1) { S[WA] = hb; } \
        barrier_lds(); \
    }

    for (int ck = 0; ck < TT / CHUNK; ++ck) {
        // ---- refill x ring for t in [ck*64, ck*64+64): coalesced float4, all waves ----
        for (int i = tid; i < BT * CHUNK * 4; i += NTHR) {   // 1024 float4 rows
            int g  = i & 3;
            int tl = (i >> 2) & (CHUNK - 1);
            int bb = i >> 8;
            const float4 v = *(const float4*)(x +
                ((size_t)(b0 + bb) * TT + (ck * CHUNK + tl)) * DD + g * 4);
            ushort4 s4;
            s4.x = bfb(v.x); s4.y = bfb(v.y); s4.z = bfb(v.z); s4.w = bfb(v.w);
            *(ushort4*)&S[tl * RS + (g >> 1) * 32 + bb * 8 + (g & 1) * 4] = s4;
        }
        __syncthreads();   // full drain; all global loads are within this refill

        // ring lanes restart at tile 0/1, others static per parity
        int r1E = ringlane ? r1ring0 : r1statE;
        int r1O = ringlane ? (RS + r1ring0) : r1statO;

        int p0 = 0;
        if (ck == 0) {   // peel: first body has no L1 yet
            BODY(r0E, r1E, r2E, wE, false)
            BODY(r0O, r1O, r2O, wO, true)
            r1E += inc; r1O += inc;
            p0 = 1;
        }
        for (int p = p0; p < CHUNK / 2; ++p) {
            BODY(r0E, r1E, r2E, wE, true)
            BODY(r0O, r1O, r2O, wO, true)
            r1E += inc; r1O += inc;
        }
    }

    // ---- post-peel: L1(511) from parity 0 (body 511 wrote h1(511), h2(510) there).
    // L0 ring lanes read r1statE: finite h2prev data, feeds only unused acc1 cols.
    {
        bf8v v0 = *(const bf8v*)&S[r0E];
        bf8v v1 = *(const bf8v*)&S[r1statE];
        bf8v v2 = *(const bf8v*)&S[r2E];
        f32x4 a10 = MFMA(w1k0_0, v0, bias10);
        a10 = MFMA(w1k1_0, v1, a10);
        a10 = MFMA(w1k2_0, v2, a10);
        f32x4 a11 = MFMA(w1k0_1, v0, bias11);
        a11 = MFMA(w1k1_1, v1, a11);
        a11 = MFMA(w1k2_1, v2, a11);
        f32x4 pre;
#pragma unroll
        for (int r = 0; r < 4; ++r) pre[r] = Tq ? a11[r] : a10[r];
        float ei = __builtin_amdgcn_exp2f(-L2E * pre[0]);
        float ef = __builtin_amdgcn_exp2f(-L2E * pre[1]);
        float eg = __builtin_amdgcn_exp2f(-2.0f * L2E * pre[2]);
        float eo = __builtin_amdgcn_exp2f(-L2E * pre[3]);
        float rig = __builtin_amdgcn_rcpf((1.0f + ei) * (1.0f + eg));
        float rf  = __builtin_amdgcn_rcpf(1.0f + ef);
        float cn = __builtin_fmaf(rf, c, (1.0f - eg) * rig);
        float ec = __builtin_amdgcn_exp2f(-2.0f * L2E * cn);
        float roc = __builtin_amdgcn_rcpf((1.0f + eo) * (1.0f + ec));
        hv = (1.0f - ec) * roc;             // valid in L1 lanes: h2(511) for (b, u)
    }

    // epilogue: L1 lanes own (batch=b, unit=u) of h2(T-1)
    if (Lb) outl[b][u] = hv;
    __syncthreads();
    if (tid < BT) {
        float s = fcb[0];
        for (int uu = 0; uu < HH; ++uu) s = __builtin_fmaf(outl[tid][uu], fcw[uu], s);
        out[b0 + tid] = sigf(s);
    }
#undef BODY
#undef MFMA
}

extern "C" void kernel_launch(void* const* d_in, const int* in_sizes, int n_in,
                              void* d_out, int out_size, void* d_ws, size_t ws_size,
                              hipStream_t stream) {
    const float* x    = (const float*)d_in[0];
    const float* Wih0 = (const float*)d_in[1];
    const float* Whh0 = (const float*)d_in[2];
    const float* bih0 = (const float*)d_in[3];
    const float* bhh0 = (const float*)d_in[4];
    const float* Wih1 = (const float*)d_in[5];
    const float* Whh1 = (const float*)d_in[6];
    const float* bih1 = (const float*)d_in[7];
    const float* bhh1 = (const float*)d_in[8];
    const float* fcw  = (const float*)d_in[9];
    const float* fcb  = (const float*)d_in[10];
    lstm_kernel<<<2048 / BT, NTHR, 0, stream>>>(x, Wih0, Whh0, bih0, bhh0,
                                                Wih1, Whh1, bih1, bhh1, fcw, fcb,
                                                (float*)d_out);
}

// Round 2
// 269.508 us; speedup vs baseline: 1.3879x; 1.3879x over previous
//
#include <hip/hip_runtime.h>

#define TT 512
#define DD 16
#define HH 48
#define BT 8       // batch rows per block -> 256 blocks, one per CU (the schedulable optimum)
#define NTHR 768   // 12 waves; every lane owns exactly one cell (8b x 48u x 2 layers)
#define CHUNK 64   // timesteps of x resident in LDS ring

// LDS (ushort units):
//  [0, 8192)       x-ring: 64 tiles x 128 (tile = 2 kgrp x 8 cols x 8)
//  [8192, 9728)    B dbuf: 2 parities x 12 kgrp x 64 (8 physical cols = batch).
//    K-space (L0, re-permuted weights): k0-47 h1prev | k48-63 x (x read from ring, not stored)
//    K-space (L1):                      k0-47 h1     | k48-95 h2prev
//    k0-47 is SHARED (h1) -> one write, mirror-read serves both layers' MFMA cols.
#define XB 8192
#define STOT (XB + 1536)

typedef short bf8v __attribute__((ext_vector_type(8)));   // 8 x bf16 bits
typedef float f32x4 __attribute__((ext_vector_type(4)));

__device__ __forceinline__ ushort bfb(float f) {
    return __builtin_bit_cast(ushort, (__bf16)f);
}

// sigmoid for the FC epilogue only
__device__ __forceinline__ float sigf(float x) {
    float e = __builtin_amdgcn_exp2f(-1.4426950408889634f * x);
    return __builtin_amdgcn_rcpf(1.0f + e);
}

// LDS-only barrier (does NOT drain vmcnt -> staged global loads stay in flight across bodies)
__device__ __forceinline__ void barrier_lds() {
    asm volatile("s_waitcnt lgkmcnt(0)\ns_barrier" ::: "memory");
}

__global__ __launch_bounds__(NTHR)
void lstm_kernel(const float* __restrict__ x,
                 const float* __restrict__ Wih0, const float* __restrict__ Whh0,
                 const float* __restrict__ bih0, const float* __restrict__ bhh0,
                 const float* __restrict__ Wih1, const float* __restrict__ Whh1,
                 const float* __restrict__ bih1, const float* __restrict__ bhh1,
                 const float* __restrict__ fcw, const float* __restrict__ fcb,
                 float* __restrict__ out)
{
    __shared__ alignas(16) ushort S[STOT];
    __shared__ float outl[BT][HH];

    const int tid  = threadIdx.x;
    const int lane = tid & 63;
    const int wave = tid >> 6;
    const int b0   = blockIdx.x * BT;

    const int colq = lane & 15;
    const int quad = lane >> 4;
    const int b    = colq & 7;            // physical batch col
    const bool hi  = (colq >= 8);         // hi: L1 cell; lo: L0 cell (both batch b)
    const int u    = wave * 4 + quad;     // unit owned in C/D: acc[r] = gate r of unit u

    const float L2E = 1.4426950408889634f;

    // ---- loop-invariant LDS addresses (ushort units) ----
    const int fbm = b * 8;                          // mirror col base (cols 8-15 alias 0-7)
    const bool ringlane = (quad >= 2) && !hi;       // r1 lanes that read x from the ring
    const int r0E = XB + quad * 64 + fbm;           // k0-31  (h1, mirror-broadcast)
    const int r0O = r0E + 768;
    const int r2E = XB + (8 + quad) * 64 + fbm;     // k64-95 (h2prev u16-47, mirror)
    const int r2O = r2E + 768;
    const int r1statE = XB + (4 + quad) * 64 + fbm; // k32-63 static part (h1 u32-47 / h2prev u0-15)
    const int r1statO = r1statE + 768;
    const int r1ring0 = (quad - 2) * 64 + colq * 8; // k48-63 = x, ring tile 0 base
    const int inc = ringlane ? 256 : 0;             // ring advance per body pair
    const int kk = hi ? 48 + u : u;                 // write: lo h1 (k=u), hi h2 (k=48+u)
    const int woff = (kk >> 3) * 64 + b * 8 + (kk & 7);
    const int wE = XB + 768 + woff;                 // parity-0 body writes parity 1
    const int wO = XB + woff;

    // ---- gate-row scale folded into weights/biases: i,f,o -> -L2E, g -> -2*L2E ----
    // so exp2(pre[r]) directly yields e^{-z} / e^{-2g}; saves 4 VALU muls per cell.
    const float fac = ((colq & 3) == 2) ? (-2.0f * L2E) : (-L2E);

    // ---- C-operand biases: acc reg r = gate type r of unit u (scaled) ----
    f32x4 bias0, bias1;
#pragma unroll
    for (int r = 0; r < 4; ++r) {
        float fr = (r == 2) ? (-2.0f * L2E) : (-L2E);
        bias0[r] = fr * (bih0[r * 48 + u] + bhh0[r * 48 + u]);
        bias1[r] = fr * (bih1[r * 48 + u] + bhh1[r * 48 + u]);
    }

    // ---- step-invariant weight A-fragments (K re-permuted for L0), pre-scaled by fac ----
    // A-frag: lane holds A[m=colq][k=quad*8+j]; interleaved gate row -> PyTorch gi:
    const int gi = (colq & 3) * 48 + wave * 4 + (colq >> 2);
    bf8v w0k0, w0k1, w1k0, w1k1, w1k2;
    {
        bf8v w;
#pragma unroll
        for (int j = 0; j < 8; ++j) {     // L0 k0-31 -> Whh0 (h1prev)
            int k = quad * 8 + j;
            w[j] = (short)bfb(fac * Whh0[gi * 48 + k]);
        }
        w0k0 = w;
#pragma unroll
        for (int j = 0; j < 8; ++j) {     // L0 k32-63: k<48 Whh0, else Wih0 (x)
            int k = 32 + quad * 8 + j;
            float v = (k < 48) ? Whh0[gi * 48 + k] : Wih0[gi * 16 + (k - 48)];
            w[j] = (short)bfb(fac * v);
        }
        w0k1 = w;
#pragma unroll
        for (int j = 0; j < 8; ++j) {     // L1 k0-31 -> Wih1 (h1)
            int k = quad * 8 + j;
            w[j] = (short)bfb(fac * Wih1[gi * 48 + k]);
        }
        w1k0 = w;
#pragma unroll
        for (int j = 0; j < 8; ++j) {     // L1 k32-63: k<48 Wih1, else Whh1 (h2prev)
            int k = 32 + quad * 8 + j;
            float v = (k < 48) ? Wih1[gi * 48 + k] : Whh1[gi * 48 + (k - 48)];
            w[j] = (short)bfb(fac * v);
        }
        w1k1 = w;
#pragma unroll
        for (int j = 0; j < 8; ++j) {     // L1 k64-95 -> Whh1 (h2prev u16-47)
            int k = 64 + quad * 8 + j;
            w[j] = (short)bfb(fac * Whh1[gi * 48 + (k - 48)]);
        }
        w1k2 = w;
    }

    // ---- refill staging: bank-conflict-free index map (wave spans all 8 bb) ----
    // i = tid (+768): g = i&3, bb = (i>>2)&7, tl = i>>5.
    // ds_write_b64 banks: bb*4 + (g&1)*2 -> 32 banks covered, 4 cyc/wave = b64 floor.
    // global: 4-lane g-runs = 64B contiguous segments.
    const int g_  = tid & 3;
    const int bb_ = (tid >> 2) & 7;
    const int tlL = tid >> 5;                       // 0..23
    const float* xpA = x + ((size_t)(b0 + bb_) * TT + tlL) * DD + g_ * 4;
    const float* xpB = xpA + 24 * DD;               // tl 24..31 (threads 0..255)
    const int saA = tlL * 128 + (g_ >> 1) * 64 + bb_ * 8 + (g_ & 1) * 4;
    const int saB = saA + 24 * 128;
    float4 st0, st1;

    // STAGE(H): issue global loads for half-block H (H = ck*2 + half, 32 tiles)
#define STAGE(Hn) { \
        st0 = *(const float4*)(xpA + (Hn) * (32 * DD)); \
        if (tid < 256) st1 = *(const float4*)(xpB + (Hn) * (32 * DD)); \
    }
    // COMMIT(H): bf16-convert + ds_write staged regs into ring half (H&1)
#define COMMIT(Hn) { \
        ushort4 s4; \
        s4.x = bfb(st0.x); s4.y = bfb(st0.y); s4.z = bfb(st0.z); s4.w = bfb(st0.w); \
        *(ushort4*)&S[saA + ((Hn) & 1) * 4096] = s4; \
        if (tid < 256) { \
            s4.x = bfb(st1.x); s4.y = bfb(st1.y); s4.z = bfb(st1.z); s4.w = bfb(st1.w); \
            *(ushort4*)&S[saB + ((Hn) & 1) * 4096] = s4; \
        } \
    }

    // ---- init: zero all of S (h1/h2prev start at 0; junk cols bounded) ----
    {
        uint* p = (uint*)S;
        for (int i = tid; i < STOT / 2; i += NTHR) p[i] = 0;
    }
    __syncthreads();

    // prologue: half 0 resident; half 1 in flight across H=0 bodies
    STAGE(0)
    COMMIT(0)
    __syncthreads();
    STAGE(1)

    float c = 0.f;     // lo: c0; hi: c1
    float hv = 0.f;

#define MFMA(A, B, C) __builtin_amdgcn_mfma_f32_16x16x32_bf16(A, B, C, 0, 0, 0)

    // Cell update, 7 transcendentals (weights pre-scaled, rig/rf rcps merged):
    //   ei=e^-i ef=e^-f eg=e^-2g eo=e^-o (direct from scaled pre)
    //   P=(1+ei)(1+eg), Q=1+ef, R=rcp(PQ); cn = R*fma(P,c,(1-eg)Q)  [= c/Q + (1-eg)/P]
    //   h = (1-ec)*rcp((1+eo)(1+ec)), ec = e^-2cn
    // body t: L0(t) + L1(t-1); 3 ds_read_b128, 5 MFMA, 1 cell, 1 ds_write_b16, 1 barrier
#define BODY(V0A, V1A, V2A, WA, DOL1) { \
        bf8v v0 = *(const bf8v*)&S[V0A]; \
        bf8v v1 = *(const bf8v*)&S[V1A]; \
        bf8v v2 = *(const bf8v*)&S[V2A]; \
        f32x4 acc0 = MFMA(w0k0, v0, bias0); \
        acc0 = MFMA(w0k1, v1, acc0); \
        f32x4 pre; \
        if (DOL1) { \
            f32x4 acc1 = MFMA(w1k0, v0, bias1); \
            acc1 = MFMA(w1k1, v1, acc1); \
            acc1 = MFMA(w1k2, v2, acc1); \
            pre[0] = hi ? acc1[0] : acc0[0]; \
            pre[1] = hi ? acc1[1] : acc0[1]; \
            pre[2] = hi ? acc1[2] : acc0[2]; \
            pre[3] = hi ? acc1[3] : acc0[3]; \
        } else { \
            pre = acc0; \
        } \
        float ei = __builtin_amdgcn_exp2f(pre[0]); \
        float ef = __builtin_amdgcn_exp2f(pre[1]); \
        float eg = __builtin_amdgcn_exp2f(pre[2]); \
        float eo = __builtin_amdgcn_exp2f(pre[3]); \
        float P = (1.0f + ei) * (1.0f + eg); \
        float Q = 1.0f + ef; \
        float R = __builtin_amdgcn_rcpf(P * Q); \
        float cn = R * __builtin_fmaf(P, c, (1.0f - eg) * Q); \
        if (!DOL1) cn = hi ? c : cn;   /* peel: keep L1 state at 0 */ \
        c = cn; \
        float ec = __builtin_amdgcn_exp2f(-2.0f * L2E * cn); \
        float roc = __builtin_amdgcn_rcpf((1.0f + eo) * (1.0f + ec)); \
        hv = (1.0f - ec) * roc; \
        ushort hb = bfb(hv); \
        if (!hi) { S[WA] = hb; } \
        else if (DOL1) { S[WA] = hb; } \
        barrier_lds(); \
    }

    int r1E = 0, r1O = 0;
    for (int H = 0; H < 16; ++H) {          // 16 half-blocks of 32 bodies (16 pairs)
        if ((H & 1) == 0) {                 // chunk start: ring lanes restart at tile 0/1
            r1E = ringlane ? r1ring0 : r1statE;
            r1O = ringlane ? (128 + r1ring0) : r1statO;
        }
        int p0 = 0;
        if (H == 0) {   // peel: first body has no L1 yet
            BODY(r0E, r1E, r2E, wE, false)
            BODY(r0O, r1O, r2O, wO, true)
            r1E += inc; r1O += inc;
            p0 = 1;
        }
        for (int p = p0; p < 16; ++p) {
            BODY(r0E, r1E, r2E, wE, true)
            BODY(r0O, r1O, r2O, wO, true)
            r1E += inc; r1O += inc;
        }
        if (H < 15) {
            COMMIT(H + 1)                   // vmcnt long satisfied (issued 32 bodies ago)
            __syncthreads();                // writes visible before H+1 bodies
            if (H < 14) STAGE(H + 2)        // after the vmcnt(0) drain, stays in flight
        }
    }

    // ---- post-peel: L1(511) from parity 0 (body 511 wrote h1(511), h2(510) there).
    // Ring lanes' r1 cols are junk for L1 (cols 0-7 unused by acc1) — bounded, in-range.
    {
        int r1p = ringlane ? (r1ring0 + 32 * 256) : r1statE;   // in-bounds junk for ring lanes
        bf8v v0 = *(const bf8v*)&S[r0E];
        bf8v v1 = *(const bf8v*)&S[r1p];
        bf8v v2 = *(const bf8v*)&S[r2E];
        f32x4 acc1 = MFMA(w1k0, v0, bias1);
        acc1 = MFMA(w1k1, v1, acc1);
        acc1 = MFMA(w1k2, v2, acc1);
        float ei = __builtin_amdgcn_exp2f(acc1[0]);
        float ef = __builtin_amdgcn_exp2f(acc1[1]);
        float eg = __builtin_amdgcn_exp2f(acc1[2]);
        float eo = __builtin_amdgcn_exp2f(acc1[3]);
        float P = (1.0f + ei) * (1.0f + eg);
        float Q = 1.0f + ef;
        float R = __builtin_amdgcn_rcpf(P * Q);
        float cn = R * __builtin_fmaf(P, c, (1.0f - eg) * Q);
        float ec = __builtin_amdgcn_exp2f(-2.0f * L2E * cn);
        float roc = __builtin_amdgcn_rcpf((1.0f + eo) * (1.0f + ec));
        hv = (1.0f - ec) * roc;             // valid in hi lanes: h2(511) for (b, u)
    }

    // epilogue: hi lanes own (batch=b, unit=u) of h2(T-1)
    if (hi) outl[b][u] = hv;
    __syncthreads();
    if (tid < BT) {
        float s = fcb[0];
        for (int uu = 0; uu < HH; ++uu) s = __builtin_fmaf(outl[tid][uu], fcw[uu], s);
        out[b0 + tid] = sigf(s);
    }
#undef BODY
#undef MFMA
#undef STAGE
#undef COMMIT
}

extern "C" void kernel_launch(void* const* d_in, const int* in_sizes, int n_in,
                              void* d_out, int out_size, void* d_ws, size_t ws_size,
                              hipStream_t stream) {
    const float* x    = (const float*)d_in[0];
    const float* Wih0 = (const float*)d_in[1];
    const float* Whh0 = (const float*)d_in[2];
    const float* bih0 = (const float*)d_in[3];
    const float* bhh0 = (const float*)d_in[4];
    const float* Wih1 = (const float*)d_in[5];
    const float* Whh1 = (const float*)d_in[6];
    const float* bih1 = (const float*)d_in[7];
    const float* bhh1 = (const float*)d_in[8];
    const float* fcw  = (const float*)d_in[9];
    const float* fcb  = (const float*)d_in[10];
    lstm_kernel<<<2048 / BT, NTHR, 0, stream>>>(x, Wih0, Whh0, bih0, bhh0,
                                                Wih1, Whh1, bih1, bhh1, fcw, fcb,
                                                (float*)d_out);
}